// Round 1
// 118.677 us; speedup vs baseline: 1.0036x; 1.0036x over previous
//
#include <hip/hip_runtime.h>

// LengthRegulator: B=16, S=512, D=384, MAX_DUR=8 -> max_len=4096
// out[b,t,:] = emb[b, searchsorted_right(cumsum(dur[b]), t), :] if t < total else 0
//
// R8: latency/TLP attack on K2 (timed region = harness fill ~61us + K1 ~3us
//     + K2 ~55us; K2 runs at ~2 TB/s vs the fill's demonstrated 6.5 TB/s on
//     the same stream -> K2 is latency-bound, not BW-bound).
//  - 4 iters x 6144 blocks (prior data: 16i/1536b < 8i/3072b; extrapolate:
//    more blocks = more TLP for the memory system).
//  - imap staged to LDS once per block (<=12 entries): removes 8 dependent
//    global short-loads per thread from the vmcnt queue; per-iteration idx
//    is now a ds_read (lgkmcnt), only gather+store remain on vmcnt.
// Kept from R6/R7: XCD-aware swizzle (2 batches/XCD, 1.5 MB emb < 4 MB L2),
// plain stores (NT regressed R4: defeats 64B write-combining), int16 idxmap.

#define BB 16
#define SS 512
#define DD 384
#define D4 (DD / 4)          // 96 float4 per row
#define MAXLEN 4096          // S * MAX_DUR
#define BATCH_F4 (MAXLEN * D4)      // 393216 float4 per batch
#define K2_ITERS 4
#define K2_CHUNK (256 * K2_ITERS)   // 1024 float4 per block
#define CHUNKS_PER_B (BATCH_F4 / K2_CHUNK)  // 384
#define MAP_ENTRIES 13       // max bt span for 1024 f4 = ceil(1024/96)+1 = 12

typedef float f32x4 __attribute__((ext_vector_type(4)));

// ---- K1: cumsum + searchsorted, 4 blocks per batch ----
__global__ __launch_bounds__(256)
void lr_prologue_kernel(const int* __restrict__ dur, short* __restrict__ idxmap) {
    __shared__ int cs[SS];
    const int b       = blockIdx.x >> 2;
    const int quarter = blockIdx.x & 3;
    const int tid     = threadIdx.x;

    // wave 0: inclusive scan of dur[b, :] into LDS
    if (tid < 64) {
        const int* drow = dur + b * SS + tid * 8;
        int loc[8];
        int run = 0;
        #pragma unroll
        for (int j = 0; j < 8; ++j) { run += drow[j]; loc[j] = run; }
        int sc = run;
        #pragma unroll
        for (int off = 1; off < 64; off <<= 1) {
            int n = __shfl_up(sc, off, 64);
            if (tid >= off) sc += n;
        }
        const int base = sc - run;
        #pragma unroll
        for (int j = 0; j < 8; ++j) cs[tid * 8 + j] = base + loc[j];
    }
    __syncthreads();

    const int total = cs[SS - 1];
    short* omap = idxmap + b * MAXLEN + quarter * 1024;
    for (int k = 0; k < 4; ++k) {
        const int t = quarter * 1024 + k * 256 + tid;
        // guarded while-loop REQUIRED: fixed 9-step unroll corrupts lo when
        // the interval converges early (R3 correctness failure).
        int lo = 0, hi = SS;
        while (lo < hi) {
            int mid = (lo + hi) >> 1;
            if (cs[mid] <= t) lo = mid + 1; else hi = mid;
        }
        if (lo > SS - 1) lo = SS - 1;            // jnp.clip
        omap[k * 256 + tid] = (short)((t < total) ? lo : -1);
    }
}

// ---- K2: gather, 4 float4 per thread, 6144 blocks, LDS-staged idx map ----
__global__ __launch_bounds__(256)
void lr_gather_kernel(const f32x4* __restrict__ emb,
                      const short* __restrict__ idxmap,
                      f32x4* __restrict__ out) {
    const unsigned x   = blockIdx.x;
    const unsigned xcd = x & 7;          // round-robin XCD assignment
    const unsigned w   = x >> 3;         // 0..767 within this XCD
    const unsigned b   = xcd + 8u * (w & 1);   // 2 batches per XCD
    const unsigned c   = w >> 1;         // chunk 0..383 within batch

    __shared__ short smap[MAP_ENTRIES];

    const unsigned base   = c * K2_CHUNK;            // f4 index of chunk start
    const unsigned bt0    = base / D4;
    const unsigned lastbt = (base + K2_CHUNK - 1) / D4;
    const unsigned nent   = lastbt - bt0 + 1;        // <= 12
    if (threadIdx.x < nent)
        smap[threadIdx.x] = idxmap[b * MAXLEN + bt0 + threadIdx.x];
    __syncthreads();

    const unsigned local0 = base + threadIdx.x;      // f4 idx within batch
    const f32x4* embb = emb + b * (SS * D4);
    f32x4* outb       = out + (size_t)b * BATCH_F4;

    #pragma unroll
    for (int k = 0; k < K2_ITERS; ++k) {
        const unsigned local = local0 + k * 256;
        const unsigned bt = local / D4;              // magic-mul const div
        const unsigned d4 = local - bt * D4;
        const int idx = (int)smap[bt - bt0];
        f32x4 v = {0.f, 0.f, 0.f, 0.f};
        if (idx >= 0) v = embb[(unsigned)idx * D4 + d4];
        outb[local] = v;
    }
}

extern "C" void kernel_launch(void* const* d_in, const int* in_sizes, int n_in,
                              void* d_out, int out_size, void* d_ws, size_t ws_size,
                              hipStream_t stream) {
    const float* text_emb  = (const float*)d_in[0];  // (16,512,384) f32
    const int*   durations = (const int*)d_in[1];    // (16,512) i32
    float* out = (float*)d_out;                      // (16,4096,384) f32

    short* idxmap = (short*)d_ws;                    // B*MAXLEN shorts = 128 KB

    lr_prologue_kernel<<<BB * 4, 256, 0, stream>>>(durations, idxmap);

    lr_gather_kernel<<<BB * CHUNKS_PER_B, 256, 0, stream>>>(
        (const f32x4*)text_emb, idxmap, (f32x4*)out);
}

// Round 2
// 116.769 us; speedup vs baseline: 1.0200x; 1.0163x over previous
//
#include <hip/hip_runtime.h>

// LengthRegulator: B=16, S=512, D=384, MAX_DUR=8 -> max_len=4096
// out[b,t,:] = emb[b, searchsorted_right(cumsum(dur[b]), t), :] if t < total else 0
//
// R9: single fused kernel. R8 post-mortem: doubling TLP (3072->6144 blocks)
//     AND removing all per-iteration global imap loads was NEUTRAL (119.1 ->
//     118.7) -> K2 is not latency/TLP-bound; its duration is a stable wall.
//     The remaining controllable term is launch structure: K1 was a 64-block
//     kernel (ramp/tail-limited, ~3-5us) + a serialization gap before K2.
//     Fuse: every gather block re-derives cumsum itself (wave-0 shfl scan of
//     512 ints, L2-hot) and binary-searches only its own <=23 row entries.
//     Deletes one dispatch + gap; scan/search preamble (~2k cycles) hides
//     under other resident blocks' memory waits (VALU pipe is ~5% busy).
// Kept (proven): 8 iters x 3072 blocks (R6 best; R7 16i/1536b regressed,
//     R8 4i/6144b neutral), XCD swizzle b = xcd + 8*(w&1) (2 batches/XCD,
//     1.5 MB emb < 4 MB L2, R6 -3.3us), plain stores (NT regressed R4),
//     guarded while-loop binary search (fixed-unroll corrupted lo, R3).

#define BB 16
#define SS 512
#define DD 384
#define D4 (DD / 4)          // 96 float4 per row
#define MAXLEN 4096          // S * MAX_DUR
#define BATCH_F4 (MAXLEN * D4)      // 393216 float4 per batch
#define K2_ITERS 8
#define K2_CHUNK (256 * K2_ITERS)   // 2048 float4 per block
#define CHUNKS_PER_B (BATCH_F4 / K2_CHUNK)  // 192
#define MAP_ENTRIES 24       // bt span of 2048 f4 = ceil(2048/96)+1 = 23

typedef float f32x4 __attribute__((ext_vector_type(4)));

__global__ __launch_bounds__(256)
void lr_fused_kernel(const int* __restrict__ dur,
                     const f32x4* __restrict__ emb,
                     f32x4* __restrict__ out) {
    __shared__ int   cs[SS];
    __shared__ short smap[MAP_ENTRIES];

    const unsigned x   = blockIdx.x;
    const unsigned xcd = x & 7;          // round-robin XCD assignment
    const unsigned w   = x >> 3;         // 0..383 within this XCD
    const unsigned b   = xcd + 8u * (w & 1);   // 2 batches per XCD
    const unsigned c   = w >> 1;         // chunk 0..191 within batch
    const int tid      = threadIdx.x;

    // ---- wave 0: inclusive scan of dur[b,:] into LDS (from proven K1) ----
    if (tid < 64) {
        const int* drow = dur + b * SS + tid * 8;
        int loc[8];
        int run = 0;
        #pragma unroll
        for (int j = 0; j < 8; ++j) { run += drow[j]; loc[j] = run; }
        int sc = run;
        #pragma unroll
        for (int off = 1; off < 64; off <<= 1) {
            int n = __shfl_up(sc, off, 64);
            if (tid >= off) sc += n;
        }
        const int base = sc - run;
        #pragma unroll
        for (int j = 0; j < 8; ++j) cs[tid * 8 + j] = base + loc[j];
    }
    __syncthreads();

    // ---- threads 0..nent-1: searchsorted for this block's row span ----
    const unsigned base_f4 = c * K2_CHUNK;               // f4 idx of chunk start
    const unsigned bt0     = base_f4 / D4;
    const unsigned lastbt  = (base_f4 + K2_CHUNK - 1) / D4;
    const unsigned nent    = lastbt - bt0 + 1;           // <= 23
    const int total        = cs[SS - 1];
    if (tid < (int)nent) {
        const int t = (int)bt0 + tid;
        // guarded while-loop REQUIRED: fixed 9-step unroll corrupts lo when
        // the interval converges early (R3 correctness failure).
        int lo = 0, hi = SS;
        while (lo < hi) {
            int mid = (lo + hi) >> 1;
            if (cs[mid] <= t) lo = mid + 1; else hi = mid;
        }
        if (lo > SS - 1) lo = SS - 1;                    // jnp.clip
        smap[tid] = (short)((t < total) ? lo : -1);
    }
    __syncthreads();

    // ---- gather: 8 float4 per thread ----
    const unsigned local0 = base_f4 + tid;               // f4 idx within batch
    const f32x4* embb = emb + b * (SS * D4);
    f32x4* outb       = out + (size_t)b * BATCH_F4;

    #pragma unroll
    for (int k = 0; k < K2_ITERS; ++k) {
        const unsigned local = local0 + k * 256;
        const unsigned bt = local / D4;                  // magic-mul const div
        const unsigned d4 = local - bt * D4;
        const int idx = (int)smap[bt - bt0];
        f32x4 v = {0.f, 0.f, 0.f, 0.f};
        if (idx >= 0) v = embb[(unsigned)idx * D4 + d4];
        outb[local] = v;
    }
}

extern "C" void kernel_launch(void* const* d_in, const int* in_sizes, int n_in,
                              void* d_out, int out_size, void* d_ws, size_t ws_size,
                              hipStream_t stream) {
    const float* text_emb  = (const float*)d_in[0];  // (16,512,384) f32
    const int*   durations = (const int*)d_in[1];    // (16,512) i32
    float* out = (float*)d_out;                      // (16,4096,384) f32
    (void)d_ws; (void)ws_size;

    lr_fused_kernel<<<BB * CHUNKS_PER_B, 256, 0, stream>>>(
        durations, (const f32x4*)text_emb, (f32x4*)out);
}

// Round 3
// 116.544 us; speedup vs baseline: 1.0219x; 1.0019x over previous
//
#include <hip/hip_runtime.h>

// LengthRegulator: B=16, S=512, D=384, MAX_DUR=8 -> max_len=4096
// out[b,t,:] = emb[b, searchsorted_right(cumsum(dur[b]), t), :] if t < total else 0
//
// R10: split the byte stream by kind. Evidence: fused gather moves ~110 MB in
//     ~56us (~2 TB/s) while the harness's own fill hits 6.6 TB/s on the SAME
//     output buffer in the SAME timed region. Kernel is not VALU-bound
//     (~1.5us of VALU), not TLP-bound (R7/R8: blocks 1536->3072 helped,
//     3072->6144 neutral), not dependency-bound (R8 LDS idxmap: neutral).
//     => the mixed gather/predicated-store stream itself is the wall, and
//     ~56% of its stores are ZEROS (E[total] ~ 1792 of 4096 rows).
//     Restructure: hipMemsetAsync zeroes the output at fill rate; the gather
//     kernel early-exits blocks entirely past `total` (uniform branch after
//     the in-block scan) and skips stores for t >= total. Gather traffic
//     drops 110 MB -> ~55 MB, zero-tail bytes ride the fast fill path.
//     NOTE net bytes rise (valid region written twice) -- intentional sharp
//     test: if gather stores were at BW roofline this HURTS ~7us; theory
//     says they are 3x off roofline, so it wins.
// Kept (proven): fused per-block scan (R9), 8 iters x 3072 blocks (R6 best),
//     XCD swizzle b = xcd + 8*(w&1) (R6 -3.3us), plain stores (NT regressed
//     R4), guarded while-loop binary search (R3 correctness).

#define BB 16
#define SS 512
#define DD 384
#define D4 (DD / 4)          // 96 float4 per row
#define MAXLEN 4096          // S * MAX_DUR
#define BATCH_F4 (MAXLEN * D4)      // 393216 float4 per batch
#define K2_ITERS 8
#define K2_CHUNK (256 * K2_ITERS)   // 2048 float4 per block
#define CHUNKS_PER_B (BATCH_F4 / K2_CHUNK)  // 192
#define MAP_ENTRIES 24       // bt span of 2048 f4 = ceil(2048/96)+1 = 23

typedef float f32x4 __attribute__((ext_vector_type(4)));

__global__ __launch_bounds__(256)
void lr_fused_kernel(const int* __restrict__ dur,
                     const f32x4* __restrict__ emb,
                     f32x4* __restrict__ out) {
    __shared__ int   cs[SS];
    __shared__ short smap[MAP_ENTRIES];

    const unsigned x   = blockIdx.x;
    const unsigned xcd = x & 7;          // round-robin XCD assignment
    const unsigned w   = x >> 3;         // 0..383 within this XCD
    const unsigned b   = xcd + 8u * (w & 1);   // 2 batches per XCD
    const unsigned c   = w >> 1;         // chunk 0..191 within batch
    const int tid      = threadIdx.x;

    // ---- wave 0: inclusive scan of dur[b,:] into LDS (proven R9) ----
    if (tid < 64) {
        const int* drow = dur + b * SS + tid * 8;
        int loc[8];
        int run = 0;
        #pragma unroll
        for (int j = 0; j < 8; ++j) { run += drow[j]; loc[j] = run; }
        int sc = run;
        #pragma unroll
        for (int off = 1; off < 64; off <<= 1) {
            int n = __shfl_up(sc, off, 64);
            if (tid >= off) sc += n;
        }
        const int base = sc - run;
        #pragma unroll
        for (int j = 0; j < 8; ++j) cs[tid * 8 + j] = base + loc[j];
    }
    __syncthreads();

    const unsigned base_f4 = c * K2_CHUNK;               // f4 idx of chunk start
    const unsigned bt0     = base_f4 / D4;
    const int total        = cs[SS - 1];

    // Whole span is past `total` -> memset already zeroed it. Uniform branch:
    // every thread returns, no thread reaches the next barrier (legal).
    if ((int)bt0 >= total) return;

    // ---- threads 0..nent-1: searchsorted for this block's row span ----
    const unsigned lastbt = (base_f4 + K2_CHUNK - 1) / D4;
    const unsigned nent   = lastbt - bt0 + 1;            // <= 23
    if (tid < (int)nent) {
        const int t = (int)bt0 + tid;
        // guarded while-loop REQUIRED: fixed 9-step unroll corrupts lo when
        // the interval converges early (R3 correctness failure).
        int lo = 0, hi = SS;
        while (lo < hi) {
            int mid = (lo + hi) >> 1;
            if (cs[mid] <= t) lo = mid + 1; else hi = mid;
        }
        if (lo > SS - 1) lo = SS - 1;                    // jnp.clip
        smap[tid] = (short)((t < total) ? lo : -1);
    }
    __syncthreads();

    // ---- gather: 8 float4 per thread, stores ONLY for valid rows ----
    const unsigned local0 = base_f4 + tid;               // f4 idx within batch
    const f32x4* embb = emb + b * (SS * D4);
    f32x4* outb       = out + (size_t)b * BATCH_F4;

    #pragma unroll
    for (int k = 0; k < K2_ITERS; ++k) {
        const unsigned local = local0 + k * 256;
        const unsigned bt = local / D4;                  // magic-mul const div
        const unsigned d4 = local - bt * D4;
        const int idx = (int)smap[bt - bt0];
        if (idx >= 0) {                                  // t < total
            outb[local] = embb[(unsigned)idx * D4 + d4];
        }
        // idx < 0: zeros already provided by hipMemsetAsync
    }
}

extern "C" void kernel_launch(void* const* d_in, const int* in_sizes, int n_in,
                              void* d_out, int out_size, void* d_ws, size_t ws_size,
                              hipStream_t stream) {
    const float* text_emb  = (const float*)d_in[0];  // (16,512,384) f32
    const int*   durations = (const int*)d_in[1];    // (16,512) i32
    float* out = (float*)d_out;                      // (16,4096,384) f32
    (void)d_ws; (void)ws_size;

    // Zero the whole output at fill rate; gather only writes valid rows.
    hipMemsetAsync(d_out, 0, out_size, stream);

    lr_fused_kernel<<<BB * CHUNKS_PER_B, 256, 0, stream>>>(
        durations, (const f32x4*)text_emb, (f32x4*)out);
}

// Round 4
// 113.045 us; speedup vs baseline: 1.0536x; 1.0310x over previous
//
#include <hip/hip_runtime.h>

// LengthRegulator: B=16, S=512, D=384, MAX_DUR=8 -> max_len=4096
// out[b,t,:] = emb[b, searchsorted_right(cumsum(dur[b]), t), :] if t < total else 0
//
// R11: single kernel, LDS row-dedup. Model from R9/R10 solve: the gather
//     moves its COMBINED read+write VMEM bytes at ~6 TB/s (L2-hit reads
//     consume the same request/fabric budget as HBM writes):
//       R9  gather 110W+110R = 220 MB -> 37us ✓
//       R10 memset 100W (15.5us) + valid-gather 48W+48R (16us) ✓ (neutral)
//     So minimize TOTAL bytes: write output exactly once (no memset), and
//     dedup reads. smap is NON-DECREASING (searchsorted of increasing t),
//     so a block's <=12 row entries collapse to ~3-4 DISTINCT emb rows
//     (E[dur]=3.5). Stage distinct rows to LDS once (~40 MB total reads vs
//     110), main loop = ds_read_b128 + pure store stream (~75% writes).
//     Predicted bytes 249 -> 163 MB => ~34us -> ~27us of kernel time.
// Structure: chunk=1024 f4, 4 iters, 6144 blocks (R8 proved this shape
//     cost-neutral); LDS = 2KB cs + 18KB rows + maps ~= 20.6 KB ->
//     7 blocks/CU = 28 waves/CU (keeps TLP; R7 says don't starve it).
// Kept (proven): fused per-block scan (R9), XCD swizzle b = xcd + 8*(w&1)
//     (R6 -3.3us), plain stores (NT regressed R4), guarded while-loop
//     binary search (R3 correctness).

#define BB 16
#define SS 512
#define DD 384
#define D4 (DD / 4)          // 96 float4 per row
#define MAXLEN 4096          // S * MAX_DUR
#define BATCH_F4 (MAXLEN * D4)      // 393216 float4 per batch
#define K2_ITERS 4
#define K2_CHUNK (256 * K2_ITERS)   // 1024 float4 per block
#define CHUNKS_PER_B (BATCH_F4 / K2_CHUNK)  // 384
#define MAP_ENTRIES 12       // max bt span of 1024 f4 = floor(1023/96)+2 = 12

typedef float f32x4 __attribute__((ext_vector_type(4)));

__global__ __launch_bounds__(256)
void lr_fused_kernel(const int* __restrict__ dur,
                     const f32x4* __restrict__ emb,
                     f32x4* __restrict__ out) {
    __shared__ int   cs[SS];
    __shared__ f32x4 rows[MAP_ENTRIES * D4];   // staged distinct emb rows
    __shared__ short eslot[MAP_ENTRIES];       // entry -> slot (-1 = zeros)
    __shared__ short rowlist[MAP_ENTRIES];     // slot -> emb row index
    __shared__ int   ushare;                   // # distinct rows

    const unsigned x   = blockIdx.x;
    const unsigned xcd = x & 7;          // round-robin XCD assignment
    const unsigned w   = x >> 3;         // 0..767 within this XCD
    const unsigned b   = xcd + 8u * (w & 1);   // 2 batches per XCD
    const unsigned c   = w >> 1;         // chunk 0..383 within batch
    const int tid      = threadIdx.x;

    // ---- wave 0: inclusive scan of dur[b,:] into LDS (proven R9) ----
    if (tid < 64) {
        const int* drow = dur + b * SS + tid * 8;
        int loc[8];
        int run = 0;
        #pragma unroll
        for (int j = 0; j < 8; ++j) { run += drow[j]; loc[j] = run; }
        int sc = run;
        #pragma unroll
        for (int off = 1; off < 64; off <<= 1) {
            int n = __shfl_up(sc, off, 64);
            if (tid >= off) sc += n;
        }
        const int base = sc - run;
        #pragma unroll
        for (int j = 0; j < 8; ++j) cs[tid * 8 + j] = base + loc[j];
    }
    __syncthreads();

    const int      total   = cs[SS - 1];
    const unsigned base_f4 = c * K2_CHUNK;               // f4 idx of chunk start
    const unsigned bt0     = base_f4 / D4;
    const unsigned lastbt  = (base_f4 + K2_CHUNK - 1) / D4;
    const unsigned nent    = lastbt - bt0 + 1;           // <= 12

    // ---- lanes 0..nent-1 (all in wave 0): searchsorted + run-dedup ----
    if (tid < (int)nent) {
        const int t = (int)bt0 + tid;
        // guarded while-loop REQUIRED: fixed 9-step unroll corrupts lo when
        // the interval converges early (R3 correctness failure).
        int lo = 0, hi = SS;
        while (lo < hi) {
            int mid = (lo + hi) >> 1;
            if (cs[mid] <= t) lo = mid + 1; else hi = mid;
        }
        if (lo > SS - 1) lo = SS - 1;                    // jnp.clip
        const int myidx = (t < total) ? lo : -1;         // -1 = zero row
        // smap values are non-decreasing; invalids are a suffix. Mark run
        // starts, prefix-sum to assign compact slots.
        const int prev  = __shfl_up(myidx, 1, 64);
        const int isnew = (myidx >= 0 && (tid == 0 || myidx != prev)) ? 1 : 0;
        int ps = isnew;
        #pragma unroll
        for (int off = 1; off < 16; off <<= 1) {         // nent <= 12 lanes
            int n = __shfl_up(ps, off, 64);
            if (tid >= off) ps += n;
        }
        eslot[tid] = (short)(myidx >= 0 ? ps - 1 : -1);
        if (isnew) rowlist[ps - 1] = (short)myidx;
        if (tid == (int)nent - 1) ushare = ps;           // distinct count
    }
    __syncthreads();

    // ---- cooperative staging of U distinct rows into LDS (L2-hit reads) ----
    const int U = ushare;
    const f32x4* embb = emb + b * (SS * D4);
    for (int f = tid; f < U * D4; f += 256) {
        const int u  = f / D4;                           // magic-mul const div
        const int cc = f - u * D4;
        rows[f] = embb[(int)rowlist[u] * D4 + cc];
    }
    __syncthreads();

    // ---- emit: ds_read_b128 + pure store stream, 4 float4/thread ----
    const unsigned local0 = base_f4 + tid;               // f4 idx within batch
    f32x4* outb = out + (size_t)b * BATCH_F4;

    #pragma unroll
    for (int k = 0; k < K2_ITERS; ++k) {
        const unsigned local = local0 + k * 256;
        const unsigned bt = local / D4;                  // magic-mul const div
        const unsigned d4 = local - bt * D4;
        const int s = (int)eslot[bt - bt0];
        f32x4 v = {0.f, 0.f, 0.f, 0.f};
        if (s >= 0) v = rows[s * D4 + d4];
        outb[local] = v;
    }
}

extern "C" void kernel_launch(void* const* d_in, const int* in_sizes, int n_in,
                              void* d_out, int out_size, void* d_ws, size_t ws_size,
                              hipStream_t stream) {
    const float* text_emb  = (const float*)d_in[0];  // (16,512,384) f32
    const int*   durations = (const int*)d_in[1];    // (16,512) i32
    float* out = (float*)d_out;                      // (16,4096,384) f32
    (void)d_ws; (void)ws_size;

    lr_fused_kernel<<<BB * CHUNKS_PER_B, 256, 0, stream>>>(
        durations, (const f32x4*)text_emb, (f32x4*)out);
}